// Round 14
// baseline (8678.773 us; speedup 1.0000x reference)
//
#include <hip/hip_runtime.h>

typedef float f32x4 __attribute__((ext_vector_type(4)));
typedef int i32x4 __attribute__((ext_vector_type(4)));

#define HDIM 2048
#define BATCH 256
#define TSTEPS 300
#define NBLK 256
#define NTHR 256

// ws layout (bytes) — R8-proven
#define W8_OFF  0u          // 4 MB  : wrec^T int8-hi, MFMA B-frag order [g][ct][kb][lane][16]
#define W2_OFF  4194304u    // 1 MB  : wrec^T 2-bit lo crumbs
#define RHI_OFF 5242880u    // 1 MB  : r hi int8, 2x[256][2048]
#define RLO_OFF 6291456u    // 1 MB  : r lo int8, 2x[256][2048]
#define WI_OFF  7340032u    // 32 KB : wi_full f32 [4][2048]
#define WO_OFF  7372800u    // 16 KB : wo_full f32 [2][2048]
#define SC_OFF  7389184u    // 8 KB  : per-col scale s[2048]
#define BAR_OFF 7397376u    // 4 KB  : barrier area

// bar u32 indices (R13-proven shape)
#define B_FLAGS 0                     // flags[256]: [xcc*32 + bi]
#define B_RDY(x) (256 + (x) * 32)     // per-XCD ready generation (128B apart)
#define B_GCNT0 520                   // init barrier counter
#define B_XTOT(x) (544 + (x))         // per-XCD registration counters

#define AGENT __HIP_MEMORY_SCOPE_AGENT

__device__ inline float tanh_fast(float x) {
  float e = __expf(2.0f * x);
  return 1.0f - 2.0f / (e + 1.0f);
}

// write-through (sc0 sc1) byte store: lands at coherence point, no dirty L2 line
// (same instruction family as R12/R13-proven global_store_short sc0 sc1).
__device__ inline void st_i8_wt(char* p, int v) {
  unsigned vv = (unsigned)(unsigned char)(char)v;
  asm volatile("global_store_byte %0, %1, off sc0 sc1" :: "v"(p), "v"(vv) : "memory");
}

// s[j] = max_k |wrec[j][k]| / 127 (verified R8)
__global__ void prep_scale(const float* __restrict__ rec_noise,
                           const float* __restrict__ m, const float* __restrict__ n,
                           float* __restrict__ s) {
  int w = threadIdx.x >> 6, l = threadIdx.x & 63;
  int j = blockIdx.x * 4 + w;
  float m0 = m[j * 2], m1 = m[j * 2 + 1];
  float vmax = 0.f;
  for (int it = 0; it < HDIM / 64; ++it) {
    int k = it * 64 + l;
    float v = rec_noise[(size_t)j * HDIM + k] + m0 * n[k * 2] + m1 * n[k * 2 + 1];
    vmax = fmaxf(vmax, fabsf(v));
  }
#pragma unroll
  for (int d = 1; d < 64; d <<= 1) vmax = fmaxf(vmax, __shfl_xor(vmax, d, 64));
  if (l == 0) s[j] = fmaxf(vmax, 1e-20f) / 127.f;
}

// int8-hi (B-frag order) + 2-bit lo crumbs (verified R8)
__global__ void prep_w8w2(const float* __restrict__ rec_noise,
                          const float* __restrict__ m, const float* __restrict__ n,
                          const float* __restrict__ s,
                          char* __restrict__ W8, unsigned* __restrict__ W2) {
  int gid = blockIdx.x * 256 + threadIdx.x;   // [0, 262144)
  int lane = gid & 63;
  int kb = (gid >> 6) & 31;
  int ct = (gid >> 11) & 3;
  int g = gid >> 13;                           // [0,32)
  int col = g * 64 + ct * 16 + (lane & 15);
  int kbase = kb * 64 + (lane >> 4) * 16;
  float sc = s[col];
  float m0 = m[col * 2], m1 = m[col * 2 + 1];
  unsigned crumbs = 0u;
  size_t b8 = (size_t)((lane << 4) | (kb << 10) | (ct << 15)) + ((size_t)g << 17);
#pragma unroll 4
  for (int i = 0; i < 16; ++i) {
    int k = kbase + i;
    float v = (rec_noise[(size_t)col * HDIM + k] + m0 * n[k * 2] + m1 * n[k * 2 + 1]) / sc;
    int q8 = __float2int_rn(v);
    q8 = max(-127, min(127, q8));
    float f = v - (float)q8;
    int q2 = (int)floorf(4.f * f);
    q2 = max(-2, min(1, q2));
    W8[b8 + i] = (char)q8;
    crumbs |= (unsigned)(q2 + 2) << (2 * i);
  }
  W2[gid] = crumbs;
}

// wi_full, wo_full, r0 hi/lo (verified R8)
__global__ void prep_small(const float* __restrict__ wi, const float* __restrict__ si,
                           const float* __restrict__ wo, const float* __restrict__ so,
                           const float* __restrict__ h0,
                           float* __restrict__ wi_full, float* __restrict__ wo_full,
                           char* __restrict__ rhi0, char* __restrict__ rlo0) {
  int idx = blockIdx.x * 256 + threadIdx.x;
  if (idx < BATCH * HDIM) {
    int j = idx & (HDIM - 1);
    int Q = __float2int_rn(16256.f * tanh_fast(h0[j]));
    int ah = (Q + 64) >> 7;
    int al = Q - (ah << 7);
    rhi0[idx] = (char)ah;
    rlo0[idx] = (char)al;
  }
  if (idx < 4 * HDIM) wi_full[idx] = wi[idx] * si[idx >> 11];
  if (idx < 2 * HDIM) {
    int o = idx >> 11, j = idx & (HDIM - 1);
    wo_full[idx] = wo[j * 2 + o] * so[o];
  }
}

// 8 independent single-XCD pipelines: XCD x owns batch rows [32x, 32x+32);
// block bi on it owns output cols [64bi, 64bi+64). Sync scope = 32 blocks, one
// XCD. Numerics = R8 (int8 hi/lo, floor-proven). Sync = R13 (write-through
// stores -> flag -> leader ACQUIRE L2-inv -> ready -> sibling L1-inv).
__global__ __launch_bounds__(NTHR, 1) void rnn_run(
    const float* __restrict__ inp, const float* __restrict__ noise,
    const char* __restrict__ W8, const unsigned* __restrict__ W2,
    char* __restrict__ rhi, char* __restrict__ rlo,
    const float* __restrict__ wi_full, const float* __restrict__ wo_full,
    const float* __restrict__ scales, const float* __restrict__ h0,
    float* __restrict__ out, unsigned* __restrict__ bar) {
  extern __shared__ char Wlds[];  // 128 KB: W-hi slice (frag order)

  const int tid = threadIdx.x;
  const int l = tid & 63, w = tid >> 6;
  const int lr = l & 15, hi = l >> 4;

  // ---- registration: XCD id + index-within-XCD (R4/R6/R8/R13-proven) ----
  if (tid == 0) {
    unsigned xcc_ = (unsigned)__builtin_amdgcn_s_getreg((31u << 11) | 20u) & 7u;  // HW_REG_XCC_ID
    unsigned idx_ = __hip_atomic_fetch_add(bar + B_XTOT(xcc_), 1u, __ATOMIC_RELAXED, AGENT);
    __hip_atomic_fetch_add(bar + B_GCNT0, 1u, __ATOMIC_RELEASE, AGENT);
    while (__hip_atomic_load(bar + B_GCNT0, __ATOMIC_RELAXED, AGENT) < (unsigned)NBLK)
      __builtin_amdgcn_s_sleep(1);
    __builtin_amdgcn_fence(__ATOMIC_ACQUIRE, "agent");
    ((unsigned*)Wlds)[0] = xcc_;
    ((unsigned*)Wlds)[1] = idx_ & 31u;
  }
  __syncthreads();
  const int xcc = (int)((unsigned*)Wlds)[0];
  const int bi = (int)((unsigned*)Wlds)[1];   // [0,32): 1 block/CU, 32 CU/XCD
  __syncthreads();

  const int rbase = xcc * 32;                  // my XCD's 32 batch rows
  const int colw = bi * 64 + w * 16 + lr;      // this lane's output column
  const int is_leader = (bi == 0);

  // one-time: W-hi slice -> LDS
  {
    const f32x4* src = (const f32x4*)(W8 + (size_t)bi * 131072);
    f32x4* dst = (f32x4*)Wlds;
    for (int u = tid; u < 8192; u += NTHR) dst[u] = src[u];
  }
  // one-time: W-lo crumbs for this wave's 16 cols -> 32 VGPRs (R8-proven mapping)
  unsigned w2r[32];
  {
    const unsigned* w2g = W2 + ((size_t)bi * 4 + w) * 2048 + l;
#pragma unroll
    for (int kb = 0; kb < 32; ++kb) w2r[kb] = w2g[kb * 64];
  }

  const float swq = scales[colw] * (1.f / 16256.f);
  const float wic0 = wi_full[colw], wic1 = wi_full[HDIM + colw];
  const float wic2 = wi_full[2 * HDIM + colw], wic3 = wi_full[3 * HDIM + colw];
  const float wo0 = wo_full[colw], wo1 = wo_full[HDIM + colw];

  float h[2][4];
  {
    float a = h0[colw];
#pragma unroll
    for (int rt = 0; rt < 2; ++rt)
#pragma unroll
      for (int q = 0; q < 4; ++q) h[rt][q] = a;
  }
  __syncthreads();

  // prefetch t=0 noise + input-dot
  float nz[2][4], xd[2][4];
#pragma unroll
  for (int rt = 0; rt < 2; ++rt)
#pragma unroll
    for (int q = 0; q < 4; ++q) {
      const int brow = rbase + rt * 16 + hi * 4 + q;
      nz[rt][q] = noise[((size_t)brow * TSTEPS + 0) * HDIM + colw];
      float4 x = *(const float4*)(inp + ((size_t)brow * TSTEPS + 0) * 4);
      xd[rt][q] = x.x * wic0 + x.y * wic1 + x.z * wic2 + x.w * wic3;
    }

  const char* ldsB = Wlds + w * 32768 + l * 16;   // + kb*1024
  unsigned* myflag = bar + B_FLAGS + xcc * 32 + bi;
  const unsigned* pollp = bar + B_FLAGS + xcc * 32 + l;   // 32 flags of my XCD

  for (int t = 0; t < TSTEPS; ++t) {
    const char* rrh = rhi + (size_t)(t & 1) * (BATCH * HDIM);
    const char* rrl = rlo + (size_t)(t & 1) * (BATCH * HDIM);
    char* rwh = rhi + (size_t)((t + 1) & 1) * (BATCH * HDIM);
    char* rwl = rlo + (size_t)((t + 1) & 1) * (BATCH * HDIM);

    // ---- GEMM: 32 rows x 64 cols x K2048, 3 int8 passes (R8-proven) ----
    const i32x4* ah0 = (const i32x4*)(rrh + (size_t)(rbase + lr) * HDIM + hi * 16);
    const i32x4* ah1 = (const i32x4*)(rrh + (size_t)(rbase + 16 + lr) * HDIM + hi * 16);
    const i32x4* al0 = (const i32x4*)(rrl + (size_t)(rbase + lr) * HDIM + hi * 16);
    const i32x4* al1 = (const i32x4*)(rrl + (size_t)(rbase + 16 + lr) * HDIM + hi * 16);
    i32x4 rh0[8], rh1[8], rl0[8], rl1[8];
#pragma unroll
    for (int i = 0; i < 8; ++i) {
      rh0[i] = ah0[i * 4]; rh1[i] = ah1[i * 4];
      rl0[i] = al0[i * 4]; rl1[i] = al1[i * 4];
    }
    i32x4 accA0 = {0,0,0,0}, accA1 = {0,0,0,0};   // ahi . q8
    i32x4 accB0 = {0,0,0,0}, accB1 = {0,0,0,0};   // alo . q8
    i32x4 accC0 = {0,0,0,0}, accC1 = {0,0,0,0};   // ahi . wlo'
#pragma unroll
    for (int kb = 0; kb < 32; ++kb) {
      i32x4 bW = *(const i32x4*)(ldsB + kb * 1024);
      unsigned v = w2r[kb];
      i32x4 bL;
#pragma unroll
      for (int g = 0; g < 4; ++g) {
        unsigned vg = (v >> (8 * g)) & 0xFFu;
        unsigned tt = (vg | (vg << 12)) & 0x000F000Fu;
        tt = (tt | (tt << 6)) & 0x03030303u;
        bL[g] = (int)__builtin_amdgcn_perm(0u, 0x0301FFFDu, tt);
      }
      i32x4 a0 = rh0[kb & 7], a1 = rh1[kb & 7];
      accA0 = __builtin_amdgcn_mfma_i32_16x16x64_i8(a0, bW, accA0, 0, 0, 0);
      accA1 = __builtin_amdgcn_mfma_i32_16x16x64_i8(a1, bW, accA1, 0, 0, 0);
      accC0 = __builtin_amdgcn_mfma_i32_16x16x64_i8(a0, bL, accC0, 0, 0, 0);
      accC1 = __builtin_amdgcn_mfma_i32_16x16x64_i8(a1, bL, accC1, 0, 0, 0);
      accB0 = __builtin_amdgcn_mfma_i32_16x16x64_i8(rl0[kb & 7], bW, accB0, 0, 0, 0);
      accB1 = __builtin_amdgcn_mfma_i32_16x16x64_i8(rl1[kb & 7], bW, accB1, 0, 0, 0);
      if (kb < 24) {
        rh0[kb & 7] = ah0[(kb + 8) * 4]; rh1[kb & 7] = ah1[(kb + 8) * 4];
        rl0[kb & 7] = al0[(kb + 8) * 4]; rl1[kb & 7] = al1[(kb + 8) * 4];
      }
    }

    // ---- h update + write r_{t+1} hi/lo write-through (no dirty L2 lines) ----
    float ro[2][4];
#pragma unroll
    for (int rt = 0; rt < 2; ++rt) {
      i32x4 A = rt ? accA1 : accA0;
      i32x4 B = rt ? accB1 : accB0;
      i32x4 C = rt ? accC1 : accC0;
#pragma unroll
      for (int q = 0; q < 4; ++q) {
        float rec = swq * (128.f * (float)A[q] + (float)B[q] + 16.f * (float)C[q]);
        float hn = 0.8f * h[rt][q] + 0.05f * nz[rt][q] + 0.2f * (rec + xd[rt][q]);
        h[rt][q] = hn;
        float r_ = tanh_fast(hn);
        ro[rt][q] = r_;
        int Q = __float2int_rn(16256.f * r_);
        int ah = (Q + 64) >> 7;
        int al = Q - (ah << 7);
        const size_t off = (size_t)(rbase + rt * 16 + hi * 4 + q) * HDIM + colw;
        st_i8_wt(rwh + off, ah);
        st_i8_wt(rwl + off, al);
      }
    }

    // ---- arrive: drain WT stores (acked at coherence point), then flag ----
    asm volatile("s_waitcnt vmcnt(0)" ::: "memory");
    __syncthreads();
    if (t + 1 < TSTEPS && tid == 0)
      __hip_atomic_store(myflag, (unsigned)(t + 1), __ATOMIC_RELAXED, AGENT);

    // ---- hidden under barrier: out_t from f32 register r (R8-proven) ----
#pragma unroll
    for (int rt = 0; rt < 2; ++rt)
#pragma unroll
      for (int q = 0; q < 4; ++q) {
        float p0 = ro[rt][q] * wo0, p1 = ro[rt][q] * wo1;
        p0 += __shfl_xor(p0, 1, 64); p1 += __shfl_xor(p1, 1, 64);
        p0 += __shfl_xor(p0, 2, 64); p1 += __shfl_xor(p1, 2, 64);
        p0 += __shfl_xor(p0, 4, 64); p1 += __shfl_xor(p1, 4, 64);
        p0 += __shfl_xor(p0, 8, 64); p1 += __shfl_xor(p1, 8, 64);
        if (lr == 0) {
          const int brow = rbase + rt * 16 + hi * 4 + q;
          float* op = out + (size_t)brow * (TSTEPS * 2) + (size_t)t * 2;
          atomicAdd(op, p0);
          atomicAdd(op + 1, p1);
        }
      }

    if (t + 1 < TSTEPS) {
      // ---- hidden under barrier: prefetch t+1 noise + input-dot ----
#pragma unroll
      for (int rt = 0; rt < 2; ++rt)
#pragma unroll
        for (int q = 0; q < 4; ++q) {
          const int brow = rbase + rt * 16 + hi * 4 + q;
          nz[rt][q] = noise[((size_t)brow * TSTEPS + (t + 1)) * HDIM + colw];
          float4 x = *(const float4*)(inp + ((size_t)brow * TSTEPS + (t + 1)) * 4);
          xd[rt][q] = x.x * wic0 + x.y * wic1 + x.z * wic2 + x.w * wic3;
        }
      // ---- wait: leader polls 32 flags (1 coalesced round), ACQUIRE (L2 inv),
      //      posts ready[xcc]; siblings poll ready. All blocks then L1-inv. ----
      if (is_leader) {
        if (w == 0) {
          const unsigned tgt = (unsigned)(t + 1);
          for (;;) {
            unsigned fv = (l < 32)
                ? __hip_atomic_load(pollp, __ATOMIC_RELAXED, AGENT)
                : tgt;
            if (__all((int)(fv >= tgt))) break;
          }
          if (l == 0) {
            __builtin_amdgcn_fence(__ATOMIC_ACQUIRE, "agent");  // inv L1+L2 (this XCD)
            __hip_atomic_store(bar + B_RDY(xcc), (unsigned)(t + 1), __ATOMIC_RELAXED, AGENT);
          }
        }
      } else {
        if (tid == 0) {
          while (__hip_atomic_load(bar + B_RDY(xcc), __ATOMIC_RELAXED, AGENT) < (unsigned)(t + 1)) {}
        }
      }
      __syncthreads();
      // per-CU L1 invalidate (L2 already inv'd by this XCD's leader)
      asm volatile("buffer_inv" ::: "memory");
      asm volatile("s_waitcnt vmcnt(0)" ::: "memory");
      __builtin_amdgcn_sched_barrier(0);
    }
  }
}

extern "C" void kernel_launch(void* const* d_in, const int* in_sizes, int n_in,
                              void* d_out, int out_size, void* d_ws, size_t ws_size,
                              hipStream_t stream) {
  const float* inp = (const float*)d_in[0];
  const float* noise = (const float*)d_in[1];
  const float* wi = (const float*)d_in[2];
  const float* si = (const float*)d_in[3];
  const float* m = (const float*)d_in[4];
  const float* n = (const float*)d_in[5];
  const float* rec_noise = (const float*)d_in[6];
  const float* wo = (const float*)d_in[7];
  const float* so = (const float*)d_in[8];
  const float* h0 = (const float*)d_in[9];

  char* ws = (char*)d_ws;
  char* W8 = ws + W8_OFF;
  unsigned* W2 = (unsigned*)(ws + W2_OFF);
  char* rhi = ws + RHI_OFF;
  char* rlo = ws + RLO_OFF;
  float* wi_full = (float*)(ws + WI_OFF);
  float* wo_full = (float*)(ws + WO_OFF);
  float* sc = (float*)(ws + SC_OFF);
  unsigned* bar = (unsigned*)(ws + BAR_OFF);
  float* outp = (float*)d_out;

  // rebuild proxy params every call (ws poisoned before timing)
  prep_scale<<<512, 256, 0, stream>>>(rec_noise, m, n, sc);
  prep_w8w2<<<1024, 256, 0, stream>>>(rec_noise, m, n, sc, W8, W2);
  prep_small<<<2048, 256, 0, stream>>>(wi, si, wo, so, h0, wi_full, wo_full, rhi, rlo);
  hipMemsetAsync(d_out, 0, (size_t)out_size * sizeof(float), stream);
  hipMemsetAsync(bar, 0, 4096, stream);

  hipFuncSetAttribute((const void*)rnn_run, hipFuncAttributeMaxDynamicSharedMemorySize, 131072);
  const char* W8c = W8;
  const unsigned* W2c = W2;
  const float* scc = sc;
  const float* wic = wi_full;
  const float* woc = wo_full;
  void* kargs[12] = {(void*)&inp, (void*)&noise, (void*)&W8c, (void*)&W2c,
                     (void*)&rhi, (void*)&rlo, (void*)&wic, (void*)&woc,
                     (void*)&scc, (void*)&h0, (void*)&outp, (void*)&bar};
  hipError_t lerr = hipLaunchCooperativeKernel((void*)rnn_run, dim3(NBLK), dim3(NTHR),
                                               kargs, 131072, stream);
  if (lerr != hipSuccess) {
    rnn_run<<<dim3(NBLK), dim3(NTHR), 131072, stream>>>(
        inp, noise, W8, W2, rhi, rlo, wi_full, wo_full, sc, h0, outp, bar);
  }
}

// Round 15
// 3994.399 us; speedup vs baseline: 2.1727x; 2.1727x over previous
//
#include <hip/hip_runtime.h>

typedef float f32x4 __attribute__((ext_vector_type(4)));
typedef __bf16 bf16x8 __attribute__((ext_vector_type(8)));

#define HDIM 2048
#define BATCH 256
#define TSTEPS 300
#define NBLK 256
#define NTHR 256

// ws layout (bytes)
#define WT_OFF 0u            // 2048*2048 bf16 = 8388608 B, MFMA B-frag order
#define RBUF_OFF 8388608u    // 2 * 256*2048 bf16 = 2097152 B (double buffer)
#define WI_OFF 10485760u     // 4*2048 f32 = 32768 B
#define WO_OFF 10518528u     // 2*2048 f32 = 16384 B  ([o][j] layout)
#define BAR_OFF 10534912u    // 4 KB barrier area

// bar u32 indices
#define B_FLAGS 0                     // flags[256]: [mg*64 + (xcc&1)*32 + idx]
#define B_RDY(x) (256 + (x) * 32)     // per-XCD ready generation (128B apart)
#define B_GCNT0 520                   // init barrier counter
#define B_XTOT(x) (544 + (x))         // per-XCD registration counters

#define AGENT __HIP_MEMORY_SCOPE_AGENT

__device__ inline float tanh_fast(float x) {
  float e = __expf(2.0f * x);
  return 1.0f - 2.0f / (e + 1.0f);
}

__device__ inline unsigned short f2bf(float f) {
  union { float f; unsigned u; } v; v.f = f;
  unsigned r = v.u + 0x7fffu + ((v.u >> 16) & 1u);
  return (unsigned short)(r >> 16);
}

// write-through (sc0 sc1) 16-bit store (R11/R12/R13-proven release building block)
__device__ inline void st_bf16_wt(unsigned short* p, unsigned short v) {
  unsigned vv = v;
  asm volatile("global_store_short %0, %1, off sc0 sc1" :: "v"(p), "v"(vv) : "memory");
}

// Build wrec^T in bf16, MFMA B-frag order (verified rounds 1-13)
__global__ void prep_wt(const float* __restrict__ rec_noise,
                        const float* __restrict__ m, const float* __restrict__ n,
                        unsigned short* __restrict__ WT) {
  int base = (blockIdx.x * 256 + threadIdx.x) * 4;
#pragma unroll
  for (int ii = 0; ii < 4; ++ii) {
    int e = base + ii;
    int i = e & 7;
    int lane = (e >> 3) & 63;
    int t16 = (e >> 9) & 1;
    int kb = (e >> 10) & 63;
    int jg = e >> 16;
    int j = jg * 32 + t16 * 16 + (lane & 15);
    int k = kb * 32 + (lane >> 4) * 8 + i;
    float v = rec_noise[(size_t)j * HDIM + k] + m[j * 2] * n[k * 2] + m[j * 2 + 1] * n[k * 2 + 1];
    WT[e] = f2bf(v);
  }
}

__global__ void prep_small(const float* __restrict__ wi, const float* __restrict__ si,
                           const float* __restrict__ wo, const float* __restrict__ so,
                           const float* __restrict__ h0,
                           float* __restrict__ wi_full, float* __restrict__ wo_full,
                           unsigned short* __restrict__ r0) {
  int idx = blockIdx.x * 256 + threadIdx.x;
  if (idx < BATCH * HDIM) {
    int j = idx & (HDIM - 1);
    r0[idx] = f2bf(tanh_fast(h0[j]));
  }
  if (idx < 4 * HDIM) wi_full[idx] = wi[idx] * si[idx >> 11];
  if (idx < 2 * HDIM) {
    int o = idx >> 11, j = idx & (HDIM - 1);
    wo_full[idx] = wo[j * 2 + o] * so[o];
  }
}

// 4 independent row-group pipelines pinned to XCD pairs (R13, champion: 3.95 ms):
// mg = xcc>>1 (64 rows), jg = (xcc&1)*32 + idx (32 cols). Barrier scope = 64
// blocks on 2 XCDs; each XCD's leader polls its group's 64 flags (one coalesced
// lane round), does the single ACQUIRE (L2 inv), posts ready[xcc].
__global__ __launch_bounds__(NTHR, 1) void rnn_run(
    const float* __restrict__ inp, const float* __restrict__ noise,
    const unsigned short* __restrict__ WT, unsigned short* __restrict__ rbuf,
    const float* __restrict__ wi_full, const float* __restrict__ wo_full,
    const float* __restrict__ h0, float* __restrict__ out,
    unsigned* __restrict__ bar) {
  extern __shared__ unsigned short Wlds[];  // 128 KB: this block's W slice

  const int tid = threadIdx.x;
  const int l = tid & 63, w = tid >> 6;
  const int lr = l & 15, hi = l >> 4;

  // ---- registration: XCD id + index-within-XCD (R4/R6/R8/R13-proven) ----
  if (tid == 0) {
    unsigned xcc_ = (unsigned)__builtin_amdgcn_s_getreg((31u << 11) | 20u) & 7u;  // HW_REG_XCC_ID
    unsigned idx_ = __hip_atomic_fetch_add(bar + B_XTOT(xcc_), 1u, __ATOMIC_RELAXED, AGENT);
    __hip_atomic_fetch_add(bar + B_GCNT0, 1u, __ATOMIC_RELEASE, AGENT);
    while (__hip_atomic_load(bar + B_GCNT0, __ATOMIC_RELAXED, AGENT) < (unsigned)NBLK)
      __builtin_amdgcn_s_sleep(1);
    __builtin_amdgcn_fence(__ATOMIC_ACQUIRE, "agent");
    ((unsigned*)Wlds)[0] = xcc_;
    ((unsigned*)Wlds)[1] = idx_ & 31u;
  }
  __syncthreads();
  const int xcc = (int)((unsigned*)Wlds)[0];
  const int bi = (int)((unsigned*)Wlds)[1];
  __syncthreads();

  const int mg = xcc >> 1;                     // row group: 64 rows, on XCDs {2mg, 2mg+1}
  const int jg = (xcc & 1) * 32 + bi;          // col group [0,64): 32 cols
  const int is_leader = (bi == 0);
  const int b0w = mg * 64 + w * 16;
  const int col0 = jg * 32 + lr;

  // one-time: W slice global -> LDS
  {
    const f32x4* src = (const f32x4*)(WT + (size_t)jg * 65536);
    f32x4* dst = (f32x4*)Wlds;
    for (int u = tid; u < 8192; u += NTHR) dst[u] = src[u];
  }
  // h in registers, MFMA C layout
  float h[2][4];
  {
    float a0 = h0[col0], a1 = h0[col0 + 16];
#pragma unroll
    for (int q = 0; q < 4; ++q) { h[0][q] = a0; h[1][q] = a1; }
  }
  float wic[4][2];
#pragma unroll
  for (int i = 0; i < 4; ++i) {
    wic[i][0] = wi_full[i * HDIM + col0];
    wic[i][1] = wi_full[i * HDIM + col0 + 16];
  }
  const float wo0a = wo_full[col0], wo0b = wo_full[col0 + 16];
  const float wo1a = wo_full[HDIM + col0], wo1b = wo_full[HDIM + col0 + 16];
  __syncthreads();

  // prefetch t=0 noise + input
  float nz[2][4]; float4 xv[4];
#pragma unroll
  for (int q = 0; q < 4; ++q) {
    const int brow = b0w + hi * 4 + q;
    const float* np = noise + ((size_t)brow * TSTEPS + 0) * HDIM;
    nz[0][q] = np[col0];
    nz[1][q] = np[col0 + 16];
    xv[q] = *(const float4*)(inp + ((size_t)brow * TSTEPS + 0) * 4);
  }

  unsigned* myflag = bar + B_FLAGS + mg * 64 + (xcc & 1) * 32 + bi;
  const unsigned* pollp = bar + B_FLAGS + mg * 64 + l;   // 64 flags of my group

  for (int t = 0; t < TSTEPS; ++t) {
    const unsigned short* rr = rbuf + (size_t)(t & 1) * (BATCH * HDIM);
    unsigned short* rw = rbuf + (size_t)((t + 1) & 1) * (BATCH * HDIM);

    // ---- rec = r_t @ wrec.T, 16-deep register-ring A pipeline (cached loads) ----
    const bf16x8* ap = (const bf16x8*)(rr + (size_t)(b0w + lr) * HDIM + hi * 8);
    bf16x8 ar[16];
#pragma unroll
    for (int i = 0; i < 16; ++i) ar[i] = ap[i * 4];
    f32x4 acc0 = {0.f, 0.f, 0.f, 0.f}, acc1 = {0.f, 0.f, 0.f, 0.f};
    const bf16x8* Ws = (const bf16x8*)Wlds;
#pragma unroll
    for (int kb = 0; kb < 64; ++kb) {
      bf16x8 a = ar[kb & 15];
      bf16x8 bA = Ws[(kb * 2 + 0) * 64 + l];
      bf16x8 bB = Ws[(kb * 2 + 1) * 64 + l];
      acc0 = __builtin_amdgcn_mfma_f32_16x16x32_bf16(a, bA, acc0, 0, 0, 0);
      acc1 = __builtin_amdgcn_mfma_f32_16x16x32_bf16(a, bB, acc1, 0, 0, 0);
      if (kb < 48) ar[kb & 15] = ap[(kb + 16) * 4];
    }

    // ---- h update + write r_{t+1} write-through (no dirty L2 lines) ----
    float ro[2][4];
#pragma unroll
    for (int q = 0; q < 4; ++q) {
      float x0 = xv[q].x * wic[0][0] + xv[q].y * wic[1][0] + xv[q].z * wic[2][0] + xv[q].w * wic[3][0];
      float x1 = xv[q].x * wic[0][1] + xv[q].y * wic[1][1] + xv[q].z * wic[2][1] + xv[q].w * wic[3][1];
      float h0n = 0.8f * h[0][q] + 0.05f * nz[0][q] + 0.2f * (acc0[q] + x0);
      float h1n = 0.8f * h[1][q] + 0.05f * nz[1][q] + 0.2f * (acc1[q] + x1);
      h[0][q] = h0n; h[1][q] = h1n;
      float r0_ = tanh_fast(h0n), r1_ = tanh_fast(h1n);
      ro[0][q] = r0_; ro[1][q] = r1_;
      const int brow = b0w + hi * 4 + q;
      unsigned short* rp = rw + (size_t)brow * HDIM;
      st_bf16_wt(rp + col0, f2bf(r0_));
      st_bf16_wt(rp + col0 + 16, f2bf(r1_));
    }

    // ---- arrive: drain write-through stores, then per-group flag ----
    asm volatile("s_waitcnt vmcnt(0)" ::: "memory");
    __syncthreads();
    if (t + 1 < TSTEPS && tid == 0)
      __hip_atomic_store(myflag, (unsigned)(t + 1), __ATOMIC_RELAXED, AGENT);

    // ---- hidden under barrier: out_t from register r ----
#pragma unroll
    for (int q = 0; q < 4; ++q) {
      float p0 = ro[0][q] * wo0a + ro[1][q] * wo0b;
      float p1 = ro[0][q] * wo1a + ro[1][q] * wo1b;
      p0 += __shfl_xor(p0, 1, 64); p1 += __shfl_xor(p1, 1, 64);
      p0 += __shfl_xor(p0, 2, 64); p1 += __shfl_xor(p1, 2, 64);
      p0 += __shfl_xor(p0, 4, 64); p1 += __shfl_xor(p1, 4, 64);
      p0 += __shfl_xor(p0, 8, 64); p1 += __shfl_xor(p1, 8, 64);
      if (lr == 0) {
        const int brow = b0w + hi * 4 + q;
        float* op = out + (size_t)brow * (TSTEPS * 2) + (size_t)t * 2;
        atomicAdd(op, p0);
        atomicAdd(op + 1, p1);
      }
    }

    if (t + 1 < TSTEPS) {
      // ---- hidden under barrier: prefetch t+1 noise + input ----
#pragma unroll
      for (int q = 0; q < 4; ++q) {
        const int brow = b0w + hi * 4 + q;
        const float* np = noise + ((size_t)brow * TSTEPS + (t + 1)) * HDIM;
        nz[0][q] = np[col0];
        nz[1][q] = np[col0 + 16];
        xv[q] = *(const float4*)(inp + ((size_t)brow * TSTEPS + (t + 1)) * 4);
      }
      // ---- wait: each XCD's leader polls its group's 64 flags (1 coalesced
      //      round), ACQUIRE (L2 inv), posts ready[xcc]; siblings poll ready. ----
      if (is_leader) {
        if (w == 0) {
          const unsigned tgt = (unsigned)(t + 1);
          for (;;) {
            unsigned fv = __hip_atomic_load(pollp, __ATOMIC_RELAXED, AGENT);
            if (__all((int)(fv >= tgt))) break;
          }
          if (l == 0) {
            __builtin_amdgcn_fence(__ATOMIC_ACQUIRE, "agent");  // inv L1+L2 (this XCD)
            __hip_atomic_store(bar + B_RDY(xcc), (unsigned)(t + 1), __ATOMIC_RELAXED, AGENT);
          }
        }
      } else {
        if (tid == 0) {
          while (__hip_atomic_load(bar + B_RDY(xcc), __ATOMIC_RELAXED, AGENT) < (unsigned)(t + 1)) {}
        }
      }
      __syncthreads();
      // per-CU L1 invalidate (L2 already inv'd by this XCD's leader)
      asm volatile("buffer_inv" ::: "memory");
      asm volatile("s_waitcnt vmcnt(0)" ::: "memory");
      __builtin_amdgcn_sched_barrier(0);
    }
  }
}

extern "C" void kernel_launch(void* const* d_in, const int* in_sizes, int n_in,
                              void* d_out, int out_size, void* d_ws, size_t ws_size,
                              hipStream_t stream) {
  const float* inp = (const float*)d_in[0];
  const float* noise = (const float*)d_in[1];
  const float* wi = (const float*)d_in[2];
  const float* si = (const float*)d_in[3];
  const float* m = (const float*)d_in[4];
  const float* n = (const float*)d_in[5];
  const float* rec_noise = (const float*)d_in[6];
  const float* wo = (const float*)d_in[7];
  const float* so = (const float*)d_in[8];
  const float* h0 = (const float*)d_in[9];

  char* ws = (char*)d_ws;
  unsigned short* WT = (unsigned short*)(ws + WT_OFF);
  unsigned short* rbuf = (unsigned short*)(ws + RBUF_OFF);
  float* wi_full = (float*)(ws + WI_OFF);
  float* wo_full = (float*)(ws + WO_OFF);
  unsigned* bar = (unsigned*)(ws + BAR_OFF);
  float* outp = (float*)d_out;

  // rebuild proxy params every call (ws is poisoned before timing)
  prep_wt<<<4096, 256, 0, stream>>>(rec_noise, m, n, WT);
  prep_small<<<2048, 256, 0, stream>>>(wi, si, wo, so, h0, wi_full, wo_full, rbuf);
  hipMemsetAsync(d_out, 0, (size_t)out_size * sizeof(float), stream);
  hipMemsetAsync(bar, 0, 4096, stream);

  hipFuncSetAttribute((const void*)rnn_run, hipFuncAttributeMaxDynamicSharedMemorySize, 131072);
  const unsigned short* WTc = WT;
  void* kargs[9] = {(void*)&inp, (void*)&noise, (void*)&WTc, (void*)&rbuf,
                    (void*)&wi_full, (void*)&wo_full, (void*)&h0, (void*)&outp,
                    (void*)&bar};
  hipError_t lerr = hipLaunchCooperativeKernel((void*)rnn_run, dim3(NBLK), dim3(NTHR),
                                               kargs, 131072, stream);
  if (lerr != hipSuccess) {
    rnn_run<<<dim3(NBLK), dim3(NTHR), 131072, stream>>>(
        inp, noise, WT, rbuf, wi_full, wo_full, h0, outp, bar);
  }
}